// Round 2
// 335.359 us; speedup vs baseline: 1.0387x; 1.0387x over previous
//
#include <hip/hip_runtime.h>
#include <cstdint>

// ---------------------------------------------------------------------------
// PaddedSoftmaxSHCSA: y = softmax(mask(scale * (xW+b)_q @ (xW+b)_k^T)) @ (xW+b)_v
// T=4096, C=2048, NF=2048, 3*NF=6144. fp32 in/out, bf16 MFMA compute.
//
// Round 9 (= Round 8 resubmit after infra failure; launch_bounds hardening):
// qkv GEMM restructured (was 124.7 us @ 827 TF, MfmaUtil 35% — the
// m97-structure barrier-drain ceiling). New qkv: 256x128 tile, BK=64, 8 waves
// (512 thr), ring-3 LDS (144 KB) with counted s_waitcnt vmcnt(6) + raw
// s_barrier — loads stay in flight ACROSS barriers (never drain in main loop),
// prefetch lead = 2 K-tiles. One barrier per 32 MFMA/wave, setprio around the
// MFMA cluster. Grid 16x48 = 768 blocks = exactly 3 rounds of 256 CUs.
// Safety: WAR — stage(kt+2) hits the slot last read in block kt-1, retired
// before the barrier each wave passes before issuing; RAW — vmcnt(6) leaves
// only stage(kt+1) in flight, so stage(kt) landed for every wave post-barrier.
// Keep: 8-chunk XOR swizzle (0 conflicts), sc/softmax/pv/prep unchanged.
// ---------------------------------------------------------------------------

#define T_DIM 4096
#define C_DIM 2048
#define NF    2048
#define N3    6144
#define NEGV  (-1e30f)

typedef __bf16 bf16x8 __attribute__((ext_vector_type(8)));
typedef __bf16 bf16x4 __attribute__((ext_vector_type(4)));
typedef float  f32x4  __attribute__((ext_vector_type(4)));

__device__ __forceinline__ void async_cp16(const void* g, void* l) {
    __builtin_amdgcn_global_load_lds(
        reinterpret_cast<const __attribute__((address_space(1))) unsigned int*>(
            reinterpret_cast<uintptr_t>(g)),
        reinterpret_cast<__attribute__((address_space(3))) unsigned int*>(
            reinterpret_cast<uintptr_t>(l)),
        16, 0, 0);
}

// Shared 128x128-tile GEMM K-loop, BK=64: C[m0..+128, n0..+128] += A @ B^T
// (used by sc and pv kernels; qkv has its own pipelined core below)
__device__ __forceinline__ void gemm_loop(const __bf16* A, const __bf16* B,
                                          int lda, int ldb, int m0, int n0,
                                          int kiters, __bf16* As, __bf16* Bs,
                                          f32x4 (&acc)[4][4]) {
    const int t    = threadIdx.x;          // 0..255
    const int wv   = t >> 6;               // wave 0..3
    const int lane = t & 63;
    const int srow = t >> 3;               // staging row 0..31 (issue 0)
    const int scol = (((t & 7) ^ (srow & 7)) << 3);  // logical col for my slot
    const int wm   = (wv >> 1) << 6;       // wave m offset 0/64
    const int wn   = (wv & 1) << 6;        // wave n offset 0/64
    const int lrow = lane & 15;
    const int kq   = lane >> 4;            // logical chunk within k-step 0..3
    const int swz  = lrow & 7;             // 16/32/64 row offsets preserve &7
    const int rc0  = ((kq ^ swz) << 3);         // k-step 0: chunks 0..3
    const int rc1  = (((kq | 4) ^ swz) << 3);   // k-step 1: chunks 4..7

    const __bf16* ga = A + (size_t)(m0 + srow) * lda + scol;
    const __bf16* gb = B + (size_t)(n0 + srow) * ldb + scol;

    for (int kk = 0; kk < kiters; ++kk) {
#pragma unroll
        for (int i = 0; i < 4; ++i) {
            async_cp16(ga + (size_t)(32 * i) * lda, &As[i * 2048 + wv * 512]);
            async_cp16(gb + (size_t)(32 * i) * ldb, &Bs[i * 2048 + wv * 512]);
        }
        ga += 64; gb += 64;
        __syncthreads();   // vmcnt(0) drain + barrier

#pragma unroll
        for (int kb = 0; kb < 2; ++kb) {
            const int rc = kb ? rc1 : rc0;
            bf16x8 af[4], bfr[4];
#pragma unroll
            for (int mi = 0; mi < 4; ++mi)
                af[mi] = *(const bf16x8*)&As[(wm + mi * 16 + lrow) * 64 + rc];
#pragma unroll
            for (int ni = 0; ni < 4; ++ni)
                bfr[ni] = *(const bf16x8*)&Bs[(wn + ni * 16 + lrow) * 64 + rc];
#pragma unroll
            for (int mi = 0; mi < 4; ++mi)
#pragma unroll
                for (int ni = 0; ni < 4; ++ni)
                    acc[mi][ni] = __builtin_amdgcn_mfma_f32_16x16x32_bf16(
                        af[mi], bfr[ni], acc[mi][ni], 0, 0, 0);
        }
        __syncthreads();   // protect LDS before next-iter staging overwrite
    }
}

// ---------------- 1. prep: cast x -> bf16  AND  transpose-cast W -----------
__global__ void prep_kernel(const float* __restrict__ x,
                            __bf16* __restrict__ xb,
                            const float* __restrict__ W,
                            __bf16* __restrict__ Wt) {
    if (blockIdx.x < 2048) {
        const int n4 = (T_DIM * C_DIM) / 4;
        const int stride = 2048 * 256;
        for (int i = blockIdx.x * 256 + threadIdx.x; i < n4; i += stride) {
            float4 v = ((const float4*)x)[i];
            bf16x4 o;
            o[0] = (__bf16)v.x; o[1] = (__bf16)v.y;
            o[2] = (__bf16)v.z; o[3] = (__bf16)v.w;
            ((bf16x4*)xb)[i] = o;
        }
        return;
    }
    __shared__ float tile[32][33];
    const int tb = blockIdx.x - 2048;
    const int bx = (tb % (N3 / 32)) * 32;  // W col / Wt row
    const int by = (tb / (N3 / 32)) * 32;  // W row / Wt col
    const int tx = threadIdx.x & 31, ty = threadIdx.x >> 5;  // (32,8)
#pragma unroll
    for (int i = 0; i < 32; i += 8)
        tile[ty + i][tx] = W[(size_t)(by + ty + i) * N3 + bx + tx];
    __syncthreads();
#pragma unroll
    for (int i = 0; i < 32; i += 8)
        Wt[(size_t)(bx + ty + i) * C_DIM + by + tx] = (__bf16)tile[tx][ty + i];
}

// epilogue helpers for 16x16 C/D: col=lane&15, row=(lane>>4)*4+r
#define EPILOG_SETUP()                                     \
    const int t = threadIdx.x, wv = t >> 6, lane = t & 63; \
    const int wm = (wv >> 1) << 6, wn = (wv & 1) << 6;     \
    const int rq = (lane >> 4) << 2, cn = lane & 15

// ---------------- 3. QKV GEMM: 256x128 tile, ring-3 counted-vmcnt pipeline -
__global__ void __launch_bounds__(512)
qkv_gemm_kernel(const __bf16* __restrict__ xb, const __bf16* __restrict__ Wt,
                const float* __restrict__ bias, __bf16* __restrict__ qb,
                __bf16* __restrict__ kb, __bf16* __restrict__ vT) {
    __shared__ __bf16 As[3][256 * 64];   // 96 KB, ring of 3 K-tiles
    __shared__ __bf16 Bs[3][128 * 64];   // 48 KB

    const int t    = threadIdx.x;        // 0..511
    const int wv   = t >> 6;             // wave 0..7
    const int lane = t & 63;
    const int srow = t >> 3;             // staging row 0..63 per issue
    const int scol = (((t & 7) ^ (srow & 7)) << 3);  // pre-swizzled src chunk
    const int m0   = blockIdx.x * 256;   // 16 m-tiles
    const int n0   = blockIdx.y * 128;   // 48 n-tiles
    const int wmo  = (wv >> 1) << 6;     // wave m offset 0/64/128/192
    const int wno  = (wv & 1) << 6;      // wave n offset 0/64
    const int lrow = lane & 15;
    const int kq   = lane >> 4;
    const int swz  = lrow & 7;
    const int rc0  = ((kq ^ swz) << 3);
    const int rc1  = (((kq | 4) ^ swz) << 3);

    const __bf16* ga = xb + (size_t)(m0 + srow) * C_DIM + scol;
    const __bf16* gb = Wt + (size_t)(n0 + srow) * C_DIM + scol;

    f32x4 acc[4][4] = {};

    // stage K-tile kt into ring slot s: A 4 issues (64 rows each), B 2 issues
    auto stage = [&](int kt, int s) {
        const __bf16* a  = ga + kt * 64;
        const __bf16* b2 = gb + kt * 64;
#pragma unroll
        for (int i = 0; i < 4; ++i)
            async_cp16(a + (size_t)(64 * i) * C_DIM, &As[s][i * 4096 + wv * 512]);
#pragma unroll
        for (int i = 0; i < 2; ++i)
            async_cp16(b2 + (size_t)(64 * i) * C_DIM, &Bs[s][i * 4096 + wv * 512]);
    };

    // consume ring slot s: 16 ds_read_b128 + 32 MFMA per wave
    auto compute = [&](int s) {
        const __bf16* Ab = As[s];
        const __bf16* Bb = Bs[s];
        bf16x8 af[4][2], bfr[4][2];
#pragma unroll
        for (int mi = 0; mi < 4; ++mi) {
            const __bf16* r = &Ab[(wmo + mi * 16 + lrow) * 64];
            af[mi][0] = *(const bf16x8*)&r[rc0];
            af[mi][1] = *(const bf16x8*)&r[rc1];
        }
#pragma unroll
        for (int ni = 0; ni < 4; ++ni) {
            const __bf16* r = &Bb[(wno + ni * 16 + lrow) * 64];
            bfr[ni][0] = *(const bf16x8*)&r[rc0];
            bfr[ni][1] = *(const bf16x8*)&r[rc1];
        }
        __builtin_amdgcn_s_setprio(1);
#pragma unroll
        for (int kh = 0; kh < 2; ++kh)
#pragma unroll
            for (int mi = 0; mi < 4; ++mi)
#pragma unroll
                for (int ni = 0; ni < 4; ++ni)
                    acc[mi][ni] = __builtin_amdgcn_mfma_f32_16x16x32_bf16(
                        af[mi][kh], bfr[ni][kh], acc[mi][ni], 0, 0, 0);
        __builtin_amdgcn_s_setprio(0);
    };

    constexpr int KT = C_DIM / 64;  // 32
    stage(0, 0);
    stage(1, 1);

    int s0 = 0, s1 = 1, s2 = 2;
    for (int kt = 0; kt < KT - 2; ++kt) {
        // my stage(kt) landed once <=6 newer (stage(kt+1)) remain in flight
        asm volatile("s_waitcnt vmcnt(6)" ::: "memory");
        __builtin_amdgcn_s_barrier();        // now everyone's stage(kt) landed
        asm volatile("" ::: "memory");
        stage(kt + 2, s2);                   // slot s2 last read in block kt-1
        compute(s0);
        int tmp = s0; s0 = s1; s1 = s2; s2 = tmp;
    }
    // kt = KT-2: stage(KT-1)'s 6 loads may still fly
    asm volatile("s_waitcnt vmcnt(6)" ::: "memory");
    __builtin_amdgcn_s_barrier();
    asm volatile("" ::: "memory");
    compute(s0);
    { int tmp = s0; s0 = s1; s1 = s2; s2 = tmp; }
    // kt = KT-1: nothing issued after stage(KT-1) -> full drain
    asm volatile("s_waitcnt vmcnt(0)" ::: "memory");
    __builtin_amdgcn_s_barrier();
    asm volatile("" ::: "memory");
    compute(s0);

    // epilogue: n-tile is entirely in q, k, or v (2048 % 128 == 0)
    const int rq = (lane >> 4) << 2, cn = lane & 15;
    if (n0 >= 2 * NF) {
#pragma unroll
        for (int mi = 0; mi < 4; ++mi)
#pragma unroll
            for (int ni = 0; ni < 4; ++ni) {
                int col = n0 + wno + ni * 16 + cn;
                float bv = bias[col];
                bf16x4 o;
#pragma unroll
                for (int r = 0; r < 4; ++r) o[r] = (__bf16)(acc[mi][ni][r] + bv);
                int row = m0 + wmo + mi * 16 + rq;
                *(bf16x4*)&vT[(size_t)(col - 2 * NF) * T_DIM + row] = o;
            }
    } else {
#pragma unroll
        for (int mi = 0; mi < 4; ++mi)
#pragma unroll
            for (int ni = 0; ni < 4; ++ni) {
                int col = n0 + wno + ni * 16 + cn;
                float bv = bias[col];
#pragma unroll
                for (int r = 0; r < 4; ++r) {
                    int row = m0 + wmo + mi * 16 + rq + r;
                    float val = acc[mi][ni][r] + bv;
                    if (col < NF)
                        qb[(size_t)row * NF + col] = (__bf16)val;
                    else
                        kb[(size_t)row * NF + (col - NF)] = (__bf16)val;
                }
            }
    }
}

// ---------------- 4. S = scale * q @ k^T (bf16; mask applied in softmax) ---
__global__ void __launch_bounds__(256)
sc_gemm_kernel(const __bf16* __restrict__ qb, const __bf16* __restrict__ kb,
               __bf16* __restrict__ S, const int* __restrict__ npadd_p) {
    int i = blockIdx.x;
    int mt = (int)((sqrtf(8.0f * (float)i + 1.0f) - 1.0f) * 0.5f);
    while ((mt + 1) * (mt + 2) / 2 <= i) ++mt;
    while (mt * (mt + 1) / 2 > i) --mt;
    int nt = i - mt * (mt + 1) / 2;
    const int m0 = mt * 128, n0 = nt * 128;
    const int npadd = *npadd_p;
    if (m0 + 128 <= npadd || n0 + 128 <= npadd) return;  // fully masked

    __shared__ __bf16 As[128 * 64];
    __shared__ __bf16 Bs[128 * 64];
    f32x4 acc[4][4] = {};
    gemm_loop(qb, kb, NF, NF, m0, n0, NF / 64, As, Bs, acc);

    const float scale = 0.022097086912079608f;  // 1/sqrt(2048)
    EPILOG_SETUP();
#pragma unroll
    for (int mi = 0; mi < 4; ++mi)
#pragma unroll
        for (int ni = 0; ni < 4; ++ni) {
            int j = n0 + wn + ni * 16 + cn;
#pragma unroll
            for (int r = 0; r < 4; ++r) {
                int row = m0 + wm + mi * 16 + rq + r;
                S[(size_t)row * T_DIM + j] = (__bf16)(acc[mi][ni][r] * scale);
            }
        }
}

// ---------------- 5. row softmax: one WAVE per row, no barriers ------------
__global__ void __launch_bounds__(256)
softmax_kernel(const __bf16* __restrict__ S, __bf16* __restrict__ P,
               const int* __restrict__ npadd_p) {
    const int wv = threadIdx.x >> 6, lane = threadIdx.x & 63;
    const int row = blockIdx.x * 4 + wv;
    const int npadd = *npadd_p;
    __bf16* prow = P + (size_t)row * T_DIM;

    if (row < npadd) {  // padding row: p == 0
        bf16x8 z = {};
#pragma unroll
        for (int c = 0; c < 8; ++c) ((bf16x8*)prow)[c * 64 + lane] = z;
        return;
    }

    const __bf16* srow = S + (size_t)row * T_DIM;
    float vals[64];
    float mx = NEGV;
#pragma unroll
    for (int c = 0; c < 8; ++c) {
        if (c * 512 > row) {  // wave-uniform skip
#pragma unroll
            for (int e = 0; e < 8; ++e) vals[c * 8 + e] = NEGV;
            continue;
        }
        int j0 = c * 512 + lane * 8;
        bf16x8 v = ((const bf16x8*)srow)[c * 64 + lane];
#pragma unroll
        for (int e = 0; e < 8; ++e) {
            float f = (j0 + e >= npadd && j0 + e <= row) ? (float)v[e] : NEGV;
            vals[c * 8 + e] = f;
            mx = fmaxf(mx, f);
        }
    }
#pragma unroll
    for (int o = 32; o > 0; o >>= 1) mx = fmaxf(mx, __shfl_xor(mx, o));

    float sm = 0.f;
#pragma unroll
    for (int k = 0; k < 64; ++k) {
        vals[k] = exp2f((vals[k] - mx) * 1.4426950408889634f);
        sm += vals[k];
    }
#pragma unroll
    for (int o = 32; o > 0; o >>= 1) sm += __shfl_xor(sm, o);
    float inv = 1.0f / sm;

#pragma unroll
    for (int c = 0; c < 8; ++c) {
        bf16x8 o;
#pragma unroll
        for (int e = 0; e < 8; ++e) o[e] = (__bf16)(vals[c * 8 + e] * inv);
        ((bf16x8*)prow)[c * 64 + lane] = o;
    }
}

// ---------------- 6. y = P @ V, split-K for the deep tiles -----------------
__global__ void __launch_bounds__(256)
pv_gemm_kernel(const __bf16* __restrict__ P, const __bf16* __restrict__ vT,
               float* __restrict__ out, const int* __restrict__ npadd_p) {
    const int idx = blockIdx.x;
    const int kskip = *npadd_p >> 6;  // BK=64 tiles fully inside padding
    int mt, nt, start, iters;
    bool atomic_out;
    if (idx < 256) {
        mt = idx & 15; nt = idx >> 4;
        int kt = (mt + 1) * 2 - kskip; if (kt < 0) kt = 0;
        start = kskip; iters = kt; atomic_out = false;
    } else {
        int j = idx - 256;
        mt = 16 + (j & 15); nt = (j >> 4) & 15;
        int half = j >> 8;
        int kt = (mt + 1) * 2 - kskip; if (kt < 0) kt = 0;
        int h0 = (kt + 1) >> 1;
        start = kskip + (half ? h0 : 0);
        iters = half ? kt - h0 : h0;
        atomic_out = true;
    }
    const int m0 = mt * 128, n0 = nt * 128;

    __shared__ __bf16 As[128 * 64];
    __shared__ __bf16 Bs[128 * 64];
    f32x4 acc[4][4] = {};
    gemm_loop(P + (size_t)start * 64, vT + (size_t)start * 64,
              T_DIM, T_DIM, m0, n0, iters, As, Bs, acc);

    EPILOG_SETUP();
#pragma unroll
    for (int mi = 0; mi < 4; ++mi)
#pragma unroll
        for (int ni = 0; ni < 4; ++ni) {
            int col = n0 + wn + ni * 16 + cn;
#pragma unroll
            for (int r = 0; r < 4; ++r) {
                int row = m0 + wm + mi * 16 + rq + r;
                float* p = &out[(size_t)row * NF + col];
                if (atomic_out) unsafeAtomicAdd(p, acc[mi][ni][r]);
                else            *p = acc[mi][ni][r];
            }
        }
}

extern "C" void kernel_launch(void* const* d_in, const int* in_sizes, int n_in,
                              void* d_out, int out_size, void* d_ws,
                              size_t ws_size, hipStream_t stream) {
    const float* x = (const float*)d_in[0];
    const float* W = (const float*)d_in[1];
    const float* b = (const float*)d_in[2];
    const int* npadd = (const int*)d_in[3];
    float* out = (float*)d_out;

    char* ws = (char*)d_ws;
    // layout (120 MB used):
    __bf16* xb = (__bf16*)(ws);                          // 16 MB [0,16)
    __bf16* Wt = (__bf16*)(ws + (16ull << 20));          // 24 MB [16,40)
    __bf16* qb = (__bf16*)(ws + (40ull << 20));          // 16 MB [40,56)
    __bf16* kb = (__bf16*)(ws + (56ull << 20));          // 16 MB [56,72)
    __bf16* vT = (__bf16*)(ws + (72ull << 20));          // 16 MB [72,88)
    __bf16* S  = (__bf16*)(ws + (88ull << 20));          // 32 MB [88,120)
    __bf16* P  = (__bf16*)(ws + (40ull << 20));          // 32 MB reuse qb+kb

    // zero the atomic-accumulated half of out (rows 2048..4095)
    hipMemsetAsync(out + (size_t)2048 * NF, 0, (size_t)2048 * NF * 4, stream);

    prep_kernel<<<2048 + (N3 / 32) * (C_DIM / 32), 256, 0, stream>>>(x, xb, W, Wt);
    qkv_gemm_kernel<<<dim3(T_DIM / 256, N3 / 128), 512, 0, stream>>>(xb, Wt, b,
                                                                     qb, kb, vT);
    sc_gemm_kernel<<<528, 256, 0, stream>>>(qb, kb, S, npadd);
    softmax_kernel<<<T_DIM / 4, 256, 0, stream>>>(S, P, npadd);
    pv_gemm_kernel<<<768, 256, 0, stream>>>(P, vT, out, npadd);
}